// Round 1
// baseline (2727.660 us; speedup 1.0000x reference)
//
#include <hip/hip_runtime.h>
#include <hip/hip_bf16.h>

// GCN 2-layer forward on gfx950.
// Pipeline (all fp32):
//   deg/dinv (shared by both layers)
//   t   = Ahat @ x            (aggregate 64 feats first: Ahat(xW) == (Ahat x)W)
//   h   = relu(t @ W1 + b1)   (LDS-tiled fp32 GEMM, N x 128)
//   y   = h @ W2              (LDS-tiled fp32 GEMM, N x 40, NO bias)
//   out = b2 + dinv^2*y + scatter(dinv[s]*dinv[d]*y[s] -> d)
// Workspace: dinv (N) | t/y (N*64, y reuses) | h (N*128)  = 193*N floats ~ 77 MB.

static constexpr int FIN = 64;
static constexpr int HID = 128;
static constexpr int CLS = 40;

__global__ __launch_bounds__(256) void k_init_deg(float* __restrict__ deg, int N) {
    int i = blockIdx.x * 256 + threadIdx.x;
    if (i < N) deg[i] = 1.0f;  // self loop
}

__global__ __launch_bounds__(256) void k_count(const int* __restrict__ dst,
                                               float* __restrict__ deg, int E) {
    int e = blockIdx.x * 256 + threadIdx.x;
    if (e < E) unsafeAtomicAdd(&deg[dst[e]], 1.0f);
}

__global__ __launch_bounds__(256) void k_rsqrt(float* __restrict__ d, int N) {
    int i = blockIdx.x * 256 + threadIdx.x;
    if (i < N) d[i] = rsqrtf(d[i]);
}

// t[i][:] = dinv[i]^2 * x[i][:]   (self-loop term), 16 float4 per row
__global__ __launch_bounds__(256) void k_init_t(const float* __restrict__ x,
                                                const float* __restrict__ dinv,
                                                float* __restrict__ t, int N) {
    int idx = blockIdx.x * 256 + threadIdx.x;
    if (idx >= N * 16) return;
    int i = idx >> 4, q = idx & 15;
    float dv = dinv[i];
    float s = dv * dv;
    float4 v = *(const float4*)&x[(size_t)i * FIN + q * 4];
    v.x *= s; v.y *= s; v.z *= s; v.w *= s;
    *(float4*)&t[(size_t)i * FIN + q * 4] = v;
}

// t[dst][:] += dinv[s]*dinv[d] * x[src][:]   (16 lanes/edge, float4 each)
__global__ __launch_bounds__(256) void k_agg1(const float* __restrict__ x,
                                              const float* __restrict__ dinv,
                                              const int* __restrict__ ei,
                                              float* __restrict__ t, int E) {
    int idx = blockIdx.x * 256 + threadIdx.x;
    if (idx >= E * 16) return;
    int e = idx >> 4, q = idx & 15;
    int s = ei[e], d = ei[E + e];
    float norm = dinv[s] * dinv[d];
    float4 v = *(const float4*)&x[(size_t)s * FIN + q * 4];
    float* o = &t[(size_t)d * FIN + q * 4];
    unsafeAtomicAdd(o + 0, norm * v.x);
    unsafeAtomicAdd(o + 1, norm * v.y);
    unsafeAtomicAdd(o + 2, norm * v.z);
    unsafeAtomicAdd(o + 3, norm * v.w);
}

// h = relu(t @ W1 + b1): 64-row tiles, 256 thr, thread tile 8 rows x 4 cols.
__global__ __launch_bounds__(256) void k_gemm1(const float* __restrict__ A,   // t [N][64]
                                               const float* __restrict__ W,   // [64][128]
                                               const float* __restrict__ bias,// [128]
                                               float* __restrict__ H, int N) {
    __shared__ float Bs[FIN][132];  // [k][col], pad 132 (16B-aligned rows, bank stagger)
    __shared__ float As[64][68];    // [row][k]
    const int tid = threadIdx.x;
    {
        const float4* W4 = (const float4*)W;  // 64*128/4 = 2048
        for (int i = tid; i < 2048; i += 256) {
            int r = i >> 5, c4 = i & 31;
            *(float4*)&Bs[r][c4 * 4] = W4[i];
        }
    }
    const int row0 = blockIdx.x * 64;
    for (int i = tid; i < 1024; i += 256) {  // 64 rows x 16 float4
        int r = i >> 4, c4 = i & 15;
        int gr = row0 + r;
        float4 v = make_float4(0.f, 0.f, 0.f, 0.f);
        if (gr < N) v = *(const float4*)&A[(size_t)gr * FIN + c4 * 4];
        *(float4*)&As[r][c4 * 4] = v;
    }
    __syncthreads();
    const int tc = tid & 31;   // cols 4*tc..+3
    const int tr = tid >> 5;   // rows 8*tr..+7
    float acc[8][4] = {};
#pragma unroll
    for (int k = 0; k < FIN; k += 4) {
        float4 bq[4];
#pragma unroll
        for (int kk = 0; kk < 4; ++kk) bq[kk] = *(const float4*)&Bs[k + kk][tc * 4];
#pragma unroll
        for (int i = 0; i < 8; ++i) {
            float4 a = *(const float4*)&As[tr * 8 + i][k];
            float* ac = acc[i];
            ac[0] = fmaf(a.x, bq[0].x, ac[0]); ac[0] = fmaf(a.y, bq[1].x, ac[0]);
            ac[0] = fmaf(a.z, bq[2].x, ac[0]); ac[0] = fmaf(a.w, bq[3].x, ac[0]);
            ac[1] = fmaf(a.x, bq[0].y, ac[1]); ac[1] = fmaf(a.y, bq[1].y, ac[1]);
            ac[1] = fmaf(a.z, bq[2].y, ac[1]); ac[1] = fmaf(a.w, bq[3].y, ac[1]);
            ac[2] = fmaf(a.x, bq[0].z, ac[2]); ac[2] = fmaf(a.y, bq[1].z, ac[2]);
            ac[2] = fmaf(a.z, bq[2].z, ac[2]); ac[2] = fmaf(a.w, bq[3].z, ac[2]);
            ac[3] = fmaf(a.x, bq[0].w, ac[3]); ac[3] = fmaf(a.y, bq[1].w, ac[3]);
            ac[3] = fmaf(a.z, bq[2].w, ac[3]); ac[3] = fmaf(a.w, bq[3].w, ac[3]);
        }
    }
    float4 bv = *(const float4*)&bias[tc * 4];
#pragma unroll
    for (int i = 0; i < 8; ++i) {
        int gr = row0 + tr * 8 + i;
        if (gr < N) {
            float4 v;
            v.x = fmaxf(acc[i][0] + bv.x, 0.f);
            v.y = fmaxf(acc[i][1] + bv.y, 0.f);
            v.z = fmaxf(acc[i][2] + bv.z, 0.f);
            v.w = fmaxf(acc[i][3] + bv.w, 0.f);
            *(float4*)&H[(size_t)gr * HID + tc * 4] = v;
        }
    }
}

// y = h @ W2 (no bias): 64-row tiles, 256 thr, thread tile 2 rows x 5 cols.
__global__ __launch_bounds__(256) void k_gemm2(const float* __restrict__ H,  // [N][128]
                                               const float* __restrict__ W,  // [128][40]
                                               float* __restrict__ Y, int N) {
    __shared__ float Bs[CLS][132];  // transposed: Bs[col][k]
    __shared__ float As[64][132];   // [row][k]
    const int tid = threadIdx.x;
    for (int i = tid; i < HID * CLS; i += 256) {
        int k = i / CLS, c = i - k * CLS;
        Bs[c][k] = W[i];
    }
    const int row0 = blockIdx.x * 64;
    for (int i = tid; i < 64 * 32; i += 256) {  // 64 rows x 32 float4
        int r = i >> 5, c4 = i & 31;
        int gr = row0 + r;
        float4 v = make_float4(0.f, 0.f, 0.f, 0.f);
        if (gr < N) v = *(const float4*)&H[(size_t)gr * HID + c4 * 4];
        *(float4*)&As[r][c4 * 4] = v;
    }
    __syncthreads();
    const int tc = tid & 7;    // cols 5*tc..+4
    const int tr = tid >> 3;   // rows 2*tr..+1
    float acc[2][5] = {};
#pragma unroll 4
    for (int k = 0; k < HID; k += 4) {
        float4 b[5];
#pragma unroll
        for (int j = 0; j < 5; ++j) b[j] = *(const float4*)&Bs[tc * 5 + j][k];
#pragma unroll
        for (int i = 0; i < 2; ++i) {
            float4 a = *(const float4*)&As[tr * 2 + i][k];
#pragma unroll
            for (int j = 0; j < 5; ++j) {
                acc[i][j] = fmaf(a.x, b[j].x,
                            fmaf(a.y, b[j].y,
                            fmaf(a.z, b[j].z,
                            fmaf(a.w, b[j].w, acc[i][j]))));
            }
        }
    }
#pragma unroll
    for (int i = 0; i < 2; ++i) {
        int gr = row0 + tr * 2 + i;
        if (gr < N) {
#pragma unroll
            for (int j = 0; j < 5; ++j) Y[(size_t)gr * CLS + tc * 5 + j] = acc[i][j];
        }
    }
}

// out[i][:] = b2[:] + dinv[i]^2 * y[i][:]   (10 float4 per row)
__global__ __launch_bounds__(256) void k_init_out(const float* __restrict__ y,
                                                  const float* __restrict__ dinv,
                                                  const float* __restrict__ b2,
                                                  float* __restrict__ out, int N) {
    int idx = blockIdx.x * 256 + threadIdx.x;
    if (idx >= N * 10) return;
    int i = idx / 10, q = idx - i * 10;
    float dv = dinv[i];
    float s = dv * dv;
    float4 v = *(const float4*)&y[(size_t)i * CLS + q * 4];
    float4 bb = *(const float4*)&b2[q * 4];
    float4 o;
    o.x = bb.x + s * v.x; o.y = bb.y + s * v.y;
    o.z = bb.z + s * v.z; o.w = bb.w + s * v.w;
    *(float4*)&out[(size_t)i * CLS + q * 4] = o;
}

// out[dst][:] += dinv[s]*dinv[d] * y[src][:]   (10 lanes/edge, float4 each)
__global__ __launch_bounds__(256) void k_agg2(const float* __restrict__ y,
                                              const float* __restrict__ dinv,
                                              const int* __restrict__ ei,
                                              float* __restrict__ out, int E) {
    int idx = blockIdx.x * 256 + threadIdx.x;
    if (idx >= E * 10) return;
    int e = idx / 10, q = idx - e * 10;
    int s = ei[e], d = ei[E + e];
    float norm = dinv[s] * dinv[d];
    float4 v = *(const float4*)&y[(size_t)s * CLS + q * 4];
    float* o = &out[(size_t)d * CLS + q * 4];
    unsafeAtomicAdd(o + 0, norm * v.x);
    unsafeAtomicAdd(o + 1, norm * v.y);
    unsafeAtomicAdd(o + 2, norm * v.z);
    unsafeAtomicAdd(o + 3, norm * v.w);
}

extern "C" void kernel_launch(void* const* d_in, const int* in_sizes, int n_in,
                              void* d_out, int out_size, void* d_ws, size_t ws_size,
                              hipStream_t stream) {
    const float* x  = (const float*)d_in[0];
    const int*   ei = (const int*)d_in[1];   // [2][E], int32 per harness convention
    const float* W1 = (const float*)d_in[2];
    const float* b1 = (const float*)d_in[3];
    const float* W2 = (const float*)d_in[4];
    const float* b2 = (const float*)d_in[5];
    float* out = (float*)d_out;

    const int N = in_sizes[0] / FIN;
    const int E = in_sizes[1] / 2;

    float* dinv = (float*)d_ws;                 // N
    float* t    = dinv + N;                     // N*FIN (reused as y: N*CLS)
    float* h    = t + (size_t)N * FIN;          // N*HID
    float* y    = t;

    dim3 blk(256);
    // degree + dinv (shared by both layers)
    hipLaunchKernelGGL(k_init_deg, dim3((N + 255) / 256), blk, 0, stream, dinv, N);
    hipLaunchKernelGGL(k_count,    dim3((E + 255) / 256), blk, 0, stream, ei + E, dinv, E);
    hipLaunchKernelGGL(k_rsqrt,    dim3((N + 255) / 256), blk, 0, stream, dinv, N);
    // layer 1: aggregate x (64 feats), then GEMM+bias+relu
    hipLaunchKernelGGL(k_init_t, dim3((N * 16 + 255) / 256), blk, 0, stream, x, dinv, t, N);
    hipLaunchKernelGGL(k_agg1,   dim3((E * 16 + 255) / 256), blk, 0, stream, x, dinv, ei, t, E);
    hipLaunchKernelGGL(k_gemm1,  dim3((N + 63) / 64), blk, 0, stream, t, W1, b1, h, N);
    // layer 2: GEMM down to 40 feats, then aggregate
    hipLaunchKernelGGL(k_gemm2,    dim3((N + 63) / 64), blk, 0, stream, h, W2, y, N);
    hipLaunchKernelGGL(k_init_out, dim3((N * 10 + 255) / 256), blk, 0, stream, y, dinv, b2, out, N);
    hipLaunchKernelGGL(k_agg2,     dim3((E * 10 + 255) / 256), blk, 0, stream, y, dinv, ei, out, E);
}

// Round 2
// 834.682 us; speedup vs baseline: 3.2679x; 3.2679x over previous
//
#include <hip/hip_runtime.h>
#include <hip/hip_bf16.h>

// GCN 2-layer forward on gfx950 — CSR gather version (no float atomics).
//
// Ahat = D^-1/2 (A+I) D^-1/2 is shared by both layers. Aggregation is linear,
// so aggregate on the cheaper side of each GEMM:
//   layer 1: t = Ahat x (64 feats), h = relu(t W1 + b1)
//   layer 2: y = h W2 (40 feats),  out = Ahat y + b2
//
// Per call: build CSR by dst (histogram -> scan -> permute), dinv = rsqrt(deg),
// then two gather-aggregations (one wave per dst row, lane = feature).
//
// Workspace: dinv(N) | t(N*64, reused as y) | h(N*128) | cnt(N) | rstart(N)
//            | cursor(N) | ssrc(E) | bsum(~N/1024)   ~ 85 MB.

static constexpr int FIN = 64;
static constexpr int HID = 128;
static constexpr int CLS = 40;

// ---------------- CSR build ----------------

__global__ __launch_bounds__(256) void k_zero(int* __restrict__ p, int n) {
    int i = blockIdx.x * 256 + threadIdx.x;
    if (i < n) p[i] = 0;
}

__global__ __launch_bounds__(256) void k_hist(const int* __restrict__ dst,
                                              int* __restrict__ cnt, int E) {
    int e = blockIdx.x * 256 + threadIdx.x;
    if (e < E) atomicAdd(&cnt[dst[e]], 1);
}

// Per-block exclusive scan over 1024 elements (256 thr x 4), block totals out.
__global__ __launch_bounds__(256) void k_scan1(const int* __restrict__ cnt,
                                               int* __restrict__ rstart,
                                               int* __restrict__ bsum, int N) {
    __shared__ int sdata[256];
    const int tid = threadIdx.x;
    const int base = blockIdx.x * 1024 + tid * 4;
    int v[4], tsum = 0;
#pragma unroll
    for (int j = 0; j < 4; ++j) {
        int idx = base + j;
        v[j] = (idx < N) ? cnt[idx] : 0;
        tsum += v[j];
    }
    sdata[tid] = tsum;
    for (int off = 1; off < 256; off <<= 1) {
        __syncthreads();
        int val = (tid >= off) ? sdata[tid - off] : 0;
        __syncthreads();
        sdata[tid] += val;
    }
    __syncthreads();
    int run = sdata[tid] - tsum;  // exclusive prefix of this thread's 4
#pragma unroll
    for (int j = 0; j < 4; ++j) {
        int idx = base + j;
        if (idx < N) rstart[idx] = run;
        run += v[j];
    }
    if (tid == 255) bsum[blockIdx.x] = sdata[255];
}

__global__ void k_scan2(int* __restrict__ bsum, int nb) {
    if (threadIdx.x == 0 && blockIdx.x == 0) {
        int run = 0;
        for (int b = 0; b < nb; ++b) { int t = bsum[b]; bsum[b] = run; run += t; }
    }
}

// Add block offsets; also init cursor and dinv = rsqrt(deg+1).
__global__ __launch_bounds__(256) void k_scan3(int* __restrict__ rstart,
                                               const int* __restrict__ bsum,
                                               int* __restrict__ cursor,
                                               const int* __restrict__ cnt,
                                               float* __restrict__ dinv, int N) {
    int i = blockIdx.x * 256 + threadIdx.x;
    if (i >= N) return;
    int rs = rstart[i] + bsum[i >> 10];
    rstart[i] = rs;
    cursor[i] = rs;
    dinv[i] = rsqrtf((float)cnt[i] + 1.0f);
}

__global__ __launch_bounds__(256) void k_permute(const int* __restrict__ ei,
                                                 int* __restrict__ cursor,
                                                 int* __restrict__ ssrc, int E) {
    int e = blockIdx.x * 256 + threadIdx.x;
    if (e >= E) return;
    int s = ei[e], d = ei[E + e];
    int slot = atomicAdd(&cursor[d], 1);
    ssrc[slot] = s;
}

// ---------------- gather-aggregate: one wave per dst row ----------------
// out[d][f] = (bias[f]) + dinv[d] * ( dinv[d]*X[d][f] + sum_s dinv[s]*X[s][f] )

template <int F, bool BIAS>
__global__ __launch_bounds__(256) void k_gather(const float* __restrict__ X,
                                                const float* __restrict__ dinv,
                                                const int* __restrict__ rstart,
                                                const int* __restrict__ cnt,
                                                const int* __restrict__ ssrc,
                                                const float* __restrict__ bias,
                                                float* __restrict__ out, int N) {
    int wid = (blockIdx.x * 256 + threadIdx.x) >> 6;  // one wave per row
    int lane = threadIdx.x & 63;
    if (wid >= N) return;
    float dv = dinv[wid];
    int st = rstart[wid], c = cnt[wid];
    float xv = (F == 64 || lane < F) ? X[(size_t)wid * F + lane] : 0.f;
    float acc = dv * xv;
    for (int i = 0; i < c; ++i) {
        int s = ssrc[st + i];
        s = __builtin_amdgcn_readfirstlane(s);
        float ds = dinv[s];
        float v = (F == 64 || lane < F) ? X[(size_t)s * F + lane] : 0.f;
        acc = fmaf(ds, v, acc);
    }
    if (F == 64 || lane < F) {
        float r = dv * acc;
        if (BIAS) r += bias[lane];
        out[(size_t)wid * F + lane] = r;
    }
}

// ---------------- GEMMs (unchanged from R1) ----------------

__global__ __launch_bounds__(256) void k_gemm1(const float* __restrict__ A,   // t [N][64]
                                               const float* __restrict__ W,   // [64][128]
                                               const float* __restrict__ bias,// [128]
                                               float* __restrict__ H, int N) {
    __shared__ float Bs[FIN][132];
    __shared__ float As[64][68];
    const int tid = threadIdx.x;
    {
        const float4* W4 = (const float4*)W;  // 2048 float4
        for (int i = tid; i < 2048; i += 256) {
            int r = i >> 5, c4 = i & 31;
            *(float4*)&Bs[r][c4 * 4] = W4[i];
        }
    }
    const int row0 = blockIdx.x * 64;
    for (int i = tid; i < 1024; i += 256) {
        int r = i >> 4, c4 = i & 15;
        int gr = row0 + r;
        float4 v = make_float4(0.f, 0.f, 0.f, 0.f);
        if (gr < N) v = *(const float4*)&A[(size_t)gr * FIN + c4 * 4];
        *(float4*)&As[r][c4 * 4] = v;
    }
    __syncthreads();
    const int tc = tid & 31;
    const int tr = tid >> 5;
    float acc[8][4] = {};
#pragma unroll
    for (int k = 0; k < FIN; k += 4) {
        float4 bq[4];
#pragma unroll
        for (int kk = 0; kk < 4; ++kk) bq[kk] = *(const float4*)&Bs[k + kk][tc * 4];
#pragma unroll
        for (int i = 0; i < 8; ++i) {
            float4 a = *(const float4*)&As[tr * 8 + i][k];
            float* ac = acc[i];
            ac[0] = fmaf(a.x, bq[0].x, ac[0]); ac[0] = fmaf(a.y, bq[1].x, ac[0]);
            ac[0] = fmaf(a.z, bq[2].x, ac[0]); ac[0] = fmaf(a.w, bq[3].x, ac[0]);
            ac[1] = fmaf(a.x, bq[0].y, ac[1]); ac[1] = fmaf(a.y, bq[1].y, ac[1]);
            ac[1] = fmaf(a.z, bq[2].y, ac[1]); ac[1] = fmaf(a.w, bq[3].y, ac[1]);
            ac[2] = fmaf(a.x, bq[0].z, ac[2]); ac[2] = fmaf(a.y, bq[1].z, ac[2]);
            ac[2] = fmaf(a.z, bq[2].z, ac[2]); ac[2] = fmaf(a.w, bq[3].z, ac[2]);
            ac[3] = fmaf(a.x, bq[0].w, ac[3]); ac[3] = fmaf(a.y, bq[1].w, ac[3]);
            ac[3] = fmaf(a.z, bq[2].w, ac[3]); ac[3] = fmaf(a.w, bq[3].w, ac[3]);
        }
    }
    float4 bv = *(const float4*)&bias[tc * 4];
#pragma unroll
    for (int i = 0; i < 8; ++i) {
        int gr = row0 + tr * 8 + i;
        if (gr < N) {
            float4 v;
            v.x = fmaxf(acc[i][0] + bv.x, 0.f);
            v.y = fmaxf(acc[i][1] + bv.y, 0.f);
            v.z = fmaxf(acc[i][2] + bv.z, 0.f);
            v.w = fmaxf(acc[i][3] + bv.w, 0.f);
            *(float4*)&H[(size_t)gr * HID + tc * 4] = v;
        }
    }
}

__global__ __launch_bounds__(256) void k_gemm2(const float* __restrict__ H,  // [N][128]
                                               const float* __restrict__ W,  // [128][40]
                                               float* __restrict__ Y, int N) {
    __shared__ float Bs[CLS][132];
    __shared__ float As[64][132];
    const int tid = threadIdx.x;
    for (int i = tid; i < HID * CLS; i += 256) {
        int k = i / CLS, c = i - k * CLS;
        Bs[c][k] = W[i];
    }
    const int row0 = blockIdx.x * 64;
    for (int i = tid; i < 64 * 32; i += 256) {
        int r = i >> 5, c4 = i & 31;
        int gr = row0 + r;
        float4 v = make_float4(0.f, 0.f, 0.f, 0.f);
        if (gr < N) v = *(const float4*)&H[(size_t)gr * HID + c4 * 4];
        *(float4*)&As[r][c4 * 4] = v;
    }
    __syncthreads();
    const int tc = tid & 7;
    const int tr = tid >> 3;
    float acc[2][5] = {};
#pragma unroll 4
    for (int k = 0; k < HID; k += 4) {
        float4 b[5];
#pragma unroll
        for (int j = 0; j < 5; ++j) b[j] = *(const float4*)&Bs[tc * 5 + j][k];
#pragma unroll
        for (int i = 0; i < 2; ++i) {
            float4 a = *(const float4*)&As[tr * 2 + i][k];
#pragma unroll
            for (int j = 0; j < 5; ++j) {
                acc[i][j] = fmaf(a.x, b[j].x,
                            fmaf(a.y, b[j].y,
                            fmaf(a.z, b[j].z,
                            fmaf(a.w, b[j].w, acc[i][j]))));
            }
        }
    }
#pragma unroll
    for (int i = 0; i < 2; ++i) {
        int gr = row0 + tr * 2 + i;
        if (gr < N) {
#pragma unroll
            for (int j = 0; j < 5; ++j) Y[(size_t)gr * CLS + tc * 5 + j] = acc[i][j];
        }
    }
}

// ---------------- launch ----------------

extern "C" void kernel_launch(void* const* d_in, const int* in_sizes, int n_in,
                              void* d_out, int out_size, void* d_ws, size_t ws_size,
                              hipStream_t stream) {
    const float* x  = (const float*)d_in[0];
    const int*   ei = (const int*)d_in[1];   // [2][E]
    const float* W1 = (const float*)d_in[2];
    const float* b1 = (const float*)d_in[3];
    const float* W2 = (const float*)d_in[4];
    const float* b2 = (const float*)d_in[5];
    float* out = (float*)d_out;

    const int N = in_sizes[0] / FIN;
    const int E = in_sizes[1] / 2;
    const int nb = (N + 1023) / 1024;

    float* dinv  = (float*)d_ws;                  // N
    float* t     = dinv + N;                      // N*FIN (reused as y)
    float* h     = t + (size_t)N * FIN;           // N*HID
    int* cnt     = (int*)(h + (size_t)N * HID);   // N
    int* rstart  = cnt + N;                       // N
    int* cursor  = rstart + N;                    // N
    int* ssrc    = cursor + N;                    // E
    int* bsum    = ssrc + E;                      // nb
    float* y     = t;

    dim3 blk(256);
    // CSR by dst + dinv
    hipLaunchKernelGGL(k_zero,    dim3((N + 255) / 256), blk, 0, stream, cnt, N);
    hipLaunchKernelGGL(k_hist,    dim3((E + 255) / 256), blk, 0, stream, ei + E, cnt, E);
    hipLaunchKernelGGL(k_scan1,   dim3(nb), blk, 0, stream, cnt, rstart, bsum, N);
    hipLaunchKernelGGL(k_scan2,   dim3(1), dim3(64), 0, stream, bsum, nb);
    hipLaunchKernelGGL(k_scan3,   dim3((N + 255) / 256), blk, 0, stream, rstart, bsum, cursor, cnt, dinv, N);
    hipLaunchKernelGGL(k_permute, dim3((E + 255) / 256), blk, 0, stream, ei, cursor, ssrc, E);
    // layer 1: aggregate (64 feats) then GEMM+bias+relu
    hipLaunchKernelGGL((k_gather<FIN, false>), dim3((N + 3) / 4), blk, 0, stream,
                       x, dinv, rstart, cnt, ssrc, (const float*)nullptr, t, N);
    hipLaunchKernelGGL(k_gemm1, dim3((N + 63) / 64), blk, 0, stream, t, W1, b1, h, N);
    // layer 2: GEMM (down to 40) then aggregate + bias
    hipLaunchKernelGGL(k_gemm2, dim3((N + 63) / 64), blk, 0, stream, h, W2, y, N);
    hipLaunchKernelGGL((k_gather<CLS, true>), dim3((N + 3) / 4), blk, 0, stream,
                       y, dinv, rstart, cnt, ssrc, b2, out, N);
}

// Round 3
// 557.198 us; speedup vs baseline: 4.8953x; 1.4980x over previous
//
#include <hip/hip_runtime.h>
#include <hip/hip_bf16.h>

// GCN 2-layer forward on gfx950 — CSR gather, spill-free GEMMs.
//
//   layer 1: t = Ahat x (64 feats), h = relu(t W1 + b1)
//   layer 2: y = h W2 (40 feats),  out = Ahat y + b2
//
// R3 changes vs R2:
//  - gemm1: #pragma unroll 2 + __launch_bounds__(256,3) to stop the 256-VGPR
//    scratch spill (R2: FETCH 201MB/WRITE 441MB of spill traffic).
//  - gemm2: A read from global (L1-broadcast reuse), LDS holds only W2
//    (21 KB -> 7 blocks/CU), unroll 2.
//  - gather: chunked shuffle — 64 edge srcs + dinv loaded in parallel per
//    chunk, broadcast via __shfl; inner loop loads are independent.

static constexpr int FIN = 64;
static constexpr int HID = 128;
static constexpr int CLS = 40;

// ---------------- CSR build ----------------

__global__ __launch_bounds__(256) void k_zero(int* __restrict__ p, int n) {
    int i = blockIdx.x * 256 + threadIdx.x;
    if (i < n) p[i] = 0;
}

__global__ __launch_bounds__(256) void k_hist(const int* __restrict__ dst,
                                              int* __restrict__ cnt, int E) {
    int e = blockIdx.x * 256 + threadIdx.x;
    if (e < E) atomicAdd(&cnt[dst[e]], 1);
}

// Per-block exclusive scan over 1024 elements (256 thr x 4), block totals out.
__global__ __launch_bounds__(256) void k_scan1(const int* __restrict__ cnt,
                                               int* __restrict__ rstart,
                                               int* __restrict__ bsum, int N) {
    __shared__ int sdata[256];
    const int tid = threadIdx.x;
    const int base = blockIdx.x * 1024 + tid * 4;
    int v[4], tsum = 0;
#pragma unroll
    for (int j = 0; j < 4; ++j) {
        int idx = base + j;
        v[j] = (idx < N) ? cnt[idx] : 0;
        tsum += v[j];
    }
    sdata[tid] = tsum;
    for (int off = 1; off < 256; off <<= 1) {
        __syncthreads();
        int val = (tid >= off) ? sdata[tid - off] : 0;
        __syncthreads();
        sdata[tid] += val;
    }
    __syncthreads();
    int run = sdata[tid] - tsum;
#pragma unroll
    for (int j = 0; j < 4; ++j) {
        int idx = base + j;
        if (idx < N) rstart[idx] = run;
        run += v[j];
    }
    if (tid == 255) bsum[blockIdx.x] = sdata[255];
}

__global__ void k_scan2(int* __restrict__ bsum, int nb) {
    if (threadIdx.x == 0 && blockIdx.x == 0) {
        int run = 0;
        for (int b = 0; b < nb; ++b) { int t = bsum[b]; bsum[b] = run; run += t; }
    }
}

__global__ __launch_bounds__(256) void k_scan3(int* __restrict__ rstart,
                                               const int* __restrict__ bsum,
                                               int* __restrict__ cursor,
                                               const int* __restrict__ cnt,
                                               float* __restrict__ dinv, int N) {
    int i = blockIdx.x * 256 + threadIdx.x;
    if (i >= N) return;
    int rs = rstart[i] + bsum[i >> 10];
    rstart[i] = rs;
    cursor[i] = rs;
    dinv[i] = rsqrtf((float)cnt[i] + 1.0f);
}

__global__ __launch_bounds__(256) void k_permute(const int* __restrict__ ei,
                                                 int* __restrict__ cursor,
                                                 int* __restrict__ ssrc, int E) {
    int e = blockIdx.x * 256 + threadIdx.x;
    if (e >= E) return;
    int s = ei[e], d = ei[E + e];
    int slot = atomicAdd(&cursor[d], 1);
    ssrc[slot] = s;
}

// ---------------- gather-aggregate: one wave per dst row ----------------
// out[d][f] = (bias[f]) + dinv[d] * ( dinv[d]*X[d][f] + sum_s dinv[s]*X[s][f] )

template <int F, bool BIAS>
__global__ __launch_bounds__(256) void k_gather(const float* __restrict__ X,
                                                const float* __restrict__ dinv,
                                                const int* __restrict__ rstart,
                                                const int* __restrict__ cnt,
                                                const int* __restrict__ ssrc,
                                                const float* __restrict__ bias,
                                                float* __restrict__ out, int N) {
    int wid = (blockIdx.x * 256 + threadIdx.x) >> 6;  // one wave per row
    int lane = threadIdx.x & 63;
    if (wid >= N) return;
    float dv = dinv[wid];
    int st = rstart[wid], c = cnt[wid];
    float xv = (F == 64 || lane < F) ? X[(size_t)wid * F + lane] : 0.f;
    float acc = dv * xv;
    for (int base = 0; base < c; base += 64) {
        int m = min(64, c - base);
        int myS = 0;
        float myD = 0.f;
        if (lane < m) {
            myS = ssrc[st + base + lane];
            myD = dinv[myS];
        }
#pragma unroll 4
        for (int j = 0; j < m; ++j) {
            int s = __shfl(myS, j);
            float ds = __shfl(myD, j);
            float v = (F == 64 || lane < F) ? X[(size_t)s * F + lane] : 0.f;
            acc = fmaf(ds, v, acc);
        }
    }
    if (F == 64 || lane < F) {
        float r = dv * acc;
        if (BIAS) r += bias[lane];
        out[(size_t)wid * F + lane] = r;
    }
}

// ---------------- GEMMs ----------------

// h = relu(t @ W1 + b1), 64-row tile, TM=8 x TN=4, unroll capped (no spill).
__global__ __launch_bounds__(256, 3) void k_gemm1(const float* __restrict__ A,   // t [N][64]
                                                  const float* __restrict__ W,   // [64][128]
                                                  const float* __restrict__ bias,// [128]
                                                  float* __restrict__ H, int N) {
    __shared__ float Bs[FIN][132];
    __shared__ float As[64][68];
    const int tid = threadIdx.x;
    {
        const float4* W4 = (const float4*)W;  // 2048 float4
        for (int i = tid; i < 2048; i += 256) {
            int r = i >> 5, c4 = i & 31;
            *(float4*)&Bs[r][c4 * 4] = W4[i];
        }
    }
    const int row0 = blockIdx.x * 64;
    for (int i = tid; i < 1024; i += 256) {
        int r = i >> 4, c4 = i & 15;
        int gr = row0 + r;
        float4 v = make_float4(0.f, 0.f, 0.f, 0.f);
        if (gr < N) v = *(const float4*)&A[(size_t)gr * FIN + c4 * 4];
        *(float4*)&As[r][c4 * 4] = v;
    }
    __syncthreads();
    const int tc = tid & 31;
    const int tr = tid >> 5;
    float acc[8][4] = {};
#pragma unroll 2
    for (int k = 0; k < FIN; k += 4) {
        float4 bq[4];
#pragma unroll
        for (int kk = 0; kk < 4; ++kk) bq[kk] = *(const float4*)&Bs[k + kk][tc * 4];
#pragma unroll
        for (int i = 0; i < 8; ++i) {
            float4 a = *(const float4*)&As[tr * 8 + i][k];
            float* ac = acc[i];
            ac[0] = fmaf(a.x, bq[0].x, ac[0]); ac[0] = fmaf(a.y, bq[1].x, ac[0]);
            ac[0] = fmaf(a.z, bq[2].x, ac[0]); ac[0] = fmaf(a.w, bq[3].x, ac[0]);
            ac[1] = fmaf(a.x, bq[0].y, ac[1]); ac[1] = fmaf(a.y, bq[1].y, ac[1]);
            ac[1] = fmaf(a.z, bq[2].y, ac[1]); ac[1] = fmaf(a.w, bq[3].y, ac[1]);
            ac[2] = fmaf(a.x, bq[0].z, ac[2]); ac[2] = fmaf(a.y, bq[1].z, ac[2]);
            ac[2] = fmaf(a.z, bq[2].z, ac[2]); ac[2] = fmaf(a.w, bq[3].z, ac[2]);
            ac[3] = fmaf(a.x, bq[0].w, ac[3]); ac[3] = fmaf(a.y, bq[1].w, ac[3]);
            ac[3] = fmaf(a.z, bq[2].w, ac[3]); ac[3] = fmaf(a.w, bq[3].w, ac[3]);
        }
    }
    float4 bv = *(const float4*)&bias[tc * 4];
#pragma unroll
    for (int i = 0; i < 8; ++i) {
        int gr = row0 + tr * 8 + i;
        if (gr < N) {
            float4 v;
            v.x = fmaxf(acc[i][0] + bv.x, 0.f);
            v.y = fmaxf(acc[i][1] + bv.y, 0.f);
            v.z = fmaxf(acc[i][2] + bv.z, 0.f);
            v.w = fmaxf(acc[i][3] + bv.w, 0.f);
            *(float4*)&H[(size_t)gr * HID + tc * 4] = v;
        }
    }
}

// y = h @ W2 (no bias). A straight from global (L1-broadcast reuse),
// LDS holds only W2 (21 KB). 64-row tile, TM=2 x TN=5.
__global__ __launch_bounds__(256, 4) void k_gemm2(const float* __restrict__ H,  // [N][128]
                                                  const float* __restrict__ W,  // [128][40]
                                                  float* __restrict__ Y, int N) {
    __shared__ float Bs[CLS][132];  // Bs[col][k]
    const int tid = threadIdx.x;
    for (int i = tid; i < HID * CLS; i += 256) {
        int k = i / CLS, c = i - k * CLS;
        Bs[c][k] = W[i];
    }
    __syncthreads();
    const int row0 = blockIdx.x * 64;
    const int tc = tid & 7;    // cols 5*tc..+4
    const int tr = tid >> 3;   // rows 2*tr..+1
    const int r0 = row0 + tr * 2;
    const int ra = min(r0, N - 1);
    const int rb = min(r0 + 1, N - 1);
    float acc[2][5] = {};
#pragma unroll 2
    for (int k = 0; k < HID; k += 4) {
        float4 b[5];
#pragma unroll
        for (int j = 0; j < 5; ++j) b[j] = *(const float4*)&Bs[tc * 5 + j][k];
        float4 a0 = *(const float4*)&H[(size_t)ra * HID + k];
        float4 a1 = *(const float4*)&H[(size_t)rb * HID + k];
#pragma unroll
        for (int j = 0; j < 5; ++j) {
            acc[0][j] = fmaf(a0.x, b[j].x, fmaf(a0.y, b[j].y,
                        fmaf(a0.z, b[j].z, fmaf(a0.w, b[j].w, acc[0][j]))));
            acc[1][j] = fmaf(a1.x, b[j].x, fmaf(a1.y, b[j].y,
                        fmaf(a1.z, b[j].z, fmaf(a1.w, b[j].w, acc[1][j]))));
        }
    }
#pragma unroll
    for (int i = 0; i < 2; ++i) {
        int gr = r0 + i;
        if (gr < N) {
#pragma unroll
            for (int j = 0; j < 5; ++j) Y[(size_t)gr * CLS + tc * 5 + j] = acc[i][j];
        }
    }
}

// ---------------- launch ----------------

extern "C" void kernel_launch(void* const* d_in, const int* in_sizes, int n_in,
                              void* d_out, int out_size, void* d_ws, size_t ws_size,
                              hipStream_t stream) {
    const float* x  = (const float*)d_in[0];
    const int*   ei = (const int*)d_in[1];   // [2][E]
    const float* W1 = (const float*)d_in[2];
    const float* b1 = (const float*)d_in[3];
    const float* W2 = (const float*)d_in[4];
    const float* b2 = (const float*)d_in[5];
    float* out = (float*)d_out;

    const int N = in_sizes[0] / FIN;
    const int E = in_sizes[1] / 2;
    const int nb = (N + 1023) / 1024;

    float* dinv  = (float*)d_ws;                  // N
    float* t     = dinv + N;                      // N*FIN (reused as y)
    float* h     = t + (size_t)N * FIN;           // N*HID
    int* cnt     = (int*)(h + (size_t)N * HID);   // N
    int* rstart  = cnt + N;                       // N
    int* cursor  = rstart + N;                    // N
    int* ssrc    = cursor + N;                    // E
    int* bsum    = ssrc + E;                      // nb
    float* y     = t;

    dim3 blk(256);
    // CSR by dst + dinv
    hipLaunchKernelGGL(k_zero,    dim3((N + 255) / 256), blk, 0, stream, cnt, N);
    hipLaunchKernelGGL(k_hist,    dim3((E + 255) / 256), blk, 0, stream, ei + E, cnt, E);
    hipLaunchKernelGGL(k_scan1,   dim3(nb), blk, 0, stream, cnt, rstart, bsum, N);
    hipLaunchKernelGGL(k_scan2,   dim3(1), dim3(64), 0, stream, bsum, nb);
    hipLaunchKernelGGL(k_scan3,   dim3((N + 255) / 256), blk, 0, stream, rstart, bsum, cursor, cnt, dinv, N);
    hipLaunchKernelGGL(k_permute, dim3((E + 255) / 256), blk, 0, stream, ei, cursor, ssrc, E);
    // layer 1: aggregate (64 feats) then GEMM+bias+relu
    hipLaunchKernelGGL((k_gather<FIN, false>), dim3((N + 3) / 4), blk, 0, stream,
                       x, dinv, rstart, cnt, ssrc, (const float*)nullptr, t, N);
    hipLaunchKernelGGL(k_gemm1, dim3((N + 63) / 64), blk, 0, stream, t, W1, b1, h, N);
    // layer 2: GEMM (down to 40) then aggregate + bias
    hipLaunchKernelGGL(k_gemm2, dim3((N + 63) / 64), blk, 0, stream, h, W2, y, N);
    hipLaunchKernelGGL((k_gather<CLS, true>), dim3((N + 3) / 4), blk, 0, stream,
                       y, dinv, rstart, cnt, ssrc, b2, out, N);
}